// Round 14
// baseline (356.631 us; speedup 1.0000x reference)
//
#include <hip/hip_runtime.h>
#include <hip/hip_bf16.h>
#include <math.h>

#define M_TOT   16384      // B*N = 4*4096
#define F_DIM   768
#define C_DIM   64
#define P_DIM   8192
#define EPSN    1e-12f
#define NEG_BIG (-3.402823466e38f)
#define NCH     16
#define PCH     (P_DIM / NCH)   // 512
#define GRP     32
#define NGRP    (P_DIM / GRP)   // 256
#define MARG    1e-2f           // >= 2 * 4e-3 hard bf16x1 screen error bound

typedef __attribute__((ext_vector_type(8))) short bf16x8;
typedef __attribute__((ext_vector_type(4))) float f32x4;
typedef unsigned short ushort_t;

__device__ inline ushort_t bf16hi(float v) {
    __hip_bfloat16 hb = __float2bfloat16(v);
    return *reinterpret_cast<ushort_t*>(&hb);
}

// ---------------- Kernel A: cn = l2norm(codebook) + bf16 round ----------------
__global__ void k_norm_cb(const float* __restrict__ cb, float* __restrict__ cn,
                          ushort_t* __restrict__ ch) {
    int wv = threadIdx.x >> 6, lane = threadIdx.x & 63;
    int row = blockIdx.x * 4 + wv;
    float v = cb[(size_t)row * C_DIM + lane];
    float s = v * v;
    #pragma unroll
    for (int o = 32; o; o >>= 1) s += __shfl_xor(s, o, 64);
    float inv = 1.0f / fmaxf(sqrtf(s), EPSN);
    float nv = v * inv;
    size_t i = (size_t)row * C_DIM + lane;
    cn[i] = nv;
    ch[i] = bf16hi(nv);
}

// ---------------- Kernel A2: w_outT[c][f] = w_out[f][c] ----------------
__global__ void k_transpose_wout(const float* __restrict__ w_out, float* __restrict__ wT) {
    int i = blockIdx.x * 256 + threadIdx.x;   // 49152 total
    int f = i >> 6, c = i & 63;
    wT[(size_t)c * F_DIM + f] = w_out[i];
}

// ---------------- Kernel B: zn = l2norm(z @ w_in^T), LDS-FREE streaming GEMM ----
// No LDS, no barriers, no DMA: per-block working set at any k-window is 4 KB of
// w lines + 2 KB of z lines (L1-resident, ~15/16 hit; w fully L2-resident).
// Per wave-kq: 6 loads = 16 distinct 16B addrs each (4-way lane broadcast).
// 8 independent acc chains + unroll-16 window hide L1/L2 latency. FMA chain per
// output is k-ascending x,y,z,w -- BITWISE identical zn to previous rounds.
#define PBM 32
__global__ __launch_bounds__(256)
void k_proj(const float* __restrict__ z, const float* __restrict__ w_in,
            float* __restrict__ zn, ushort_t* __restrict__ zh) {
    const int t  = threadIdx.x;
    const int m0 = blockIdx.x * PBM;
    const int r0 = (t >> 4) * 2;        // rows r0..r0+1  (t>>4 in 0..15)
    const int c0 = (t & 15) * 4;        // cols c0..c0+3

    const float* zr0 = z + (size_t)(m0 + r0) * F_DIM;
    const float* zr1 = z + (size_t)(m0 + r0 + 1) * F_DIM;
    const float* wr0 = w_in + (size_t)(c0 + 0) * F_DIM;
    const float* wr1 = w_in + (size_t)(c0 + 1) * F_DIM;
    const float* wr2 = w_in + (size_t)(c0 + 2) * F_DIM;
    const float* wr3 = w_in + (size_t)(c0 + 3) * F_DIM;

    float acc[2][4];
    #pragma unroll
    for (int i = 0; i < 2; ++i)
        #pragma unroll
        for (int j = 0; j < 4; ++j) acc[i][j] = 0.0f;

    for (int k0 = 0; k0 < F_DIM; k0 += 64) {
        #pragma unroll
        for (int kq = 0; kq < 16; ++kq) {
            int k = k0 + kq * 4;
            float4 zf[2], wf[4];
            zf[0] = *(const float4*)(zr0 + k);
            zf[1] = *(const float4*)(zr1 + k);
            wf[0] = *(const float4*)(wr0 + k);
            wf[1] = *(const float4*)(wr1 + k);
            wf[2] = *(const float4*)(wr2 + k);
            wf[3] = *(const float4*)(wr3 + k);
            #pragma unroll
            for (int ri = 0; ri < 2; ++ri)
                #pragma unroll
                for (int cj = 0; cj < 4; ++cj) {
                    acc[ri][cj] = fmaf(zf[ri].x, wf[cj].x, acc[ri][cj]);
                    acc[ri][cj] = fmaf(zf[ri].y, wf[cj].y, acc[ri][cj]);
                    acc[ri][cj] = fmaf(zf[ri].z, wf[cj].z, acc[ri][cj]);
                    acc[ri][cj] = fmaf(zf[ri].w, wf[cj].w, acc[ri][cj]);
                }
        }
    }

    // ---- epilogue: row-norm (16-lane group holds one row's 64 c) ----
    #pragma unroll
    for (int ri = 0; ri < 2; ++ri) {
        float s = acc[ri][0] * acc[ri][0] + acc[ri][1] * acc[ri][1]
                + acc[ri][2] * acc[ri][2] + acc[ri][3] * acc[ri][3];
        #pragma unroll
        for (int o = 1; o < 16; o <<= 1) s += __shfl_xor(s, o, 64);
        float inv = 1.0f / fmaxf(sqrtf(s), EPSN);
        float4 v;
        v.x = acc[ri][0] * inv; v.y = acc[ri][1] * inv;
        v.z = acc[ri][2] * inv; v.w = acc[ri][3] * inv;
        size_t base = (size_t)(m0 + r0 + ri) * C_DIM + c0;
        *(float4*)(zn + base) = v;
        ushort4 hv = {bf16hi(v.x), bf16hi(v.y), bf16hi(v.z), bf16hi(v.w)};
        *(ushort4*)(zh + base) = hv;
    }
}

// ---------------- Kernel C: bf16x1 MFMA screen -> per-32-code group maxima ----------
// NCH=16 (r11 traffic shape: FETCH ~10 MB). A-stream (ch tiles) register
// double-buffered with NAMED regs (no runtime-indexed arrays): tile pt+1's
// loads issue before tile pt's MFMAs -> L2 latency hides under 8 MFMAs + 4
// waves/SIMD interleave. gmax[NGRP][M_TOT] hosted in d_out 'out' region.
__global__ __launch_bounds__(256, 4)
void k_simmax(const ushort_t* __restrict__ zh, const ushort_t* __restrict__ ch,
              float* __restrict__ gmax) {
    int wv = threadIdx.x >> 6, l = threadIdx.x & 63;
    int m0 = (blockIdx.x * 4 + wv) * 64;
    int p0 = blockIdx.y * PCH;
    int col = l & 15, quad = l >> 4;
    int kb = quad * 8;

    bf16x8 bh[4][2];
    #pragma unroll
    for (int mt = 0; mt < 4; ++mt) {
        const ushort_t* zr = zh + (size_t)(m0 + mt * 16 + col) * C_DIM + kb;
        #pragma unroll
        for (int ks = 0; ks < 2; ++ks)
            bh[mt][ks] = *(const bf16x8*)(zr + ks * 32);
    }

    const ushort_t* abase = ch + (size_t)(p0 + col) * C_DIM + kb;
    #define ALOAD(pt, a0, a1) do {                                        \
        const ushort_t* _p = abase + (size_t)(pt) * 16 * C_DIM;           \
        a0 = *(const bf16x8*)(_p);                                        \
        a1 = *(const bf16x8*)(_p + 32);                                   \
    } while (0)

    bf16x8 a0c, a1c, a0n, a1n;
    ALOAD(0, a0c, a1c);

    for (int g = 0; g < PCH / GRP; ++g) {           // 16 groups = 32 tiles
        float gm[4];
        #pragma unroll
        for (int mt = 0; mt < 4; ++mt) gm[mt] = NEG_BIG;

        ALOAD(2 * g + 1, a0n, a1n);                 // prefetch odd tile
        #pragma unroll
        for (int mt = 0; mt < 4; ++mt) {            // even tile MFMAs
            f32x4 acc = {0.f, 0.f, 0.f, 0.f};
            acc = __builtin_amdgcn_mfma_f32_16x16x32_bf16(a0c, bh[mt][0], acc, 0, 0, 0);
            acc = __builtin_amdgcn_mfma_f32_16x16x32_bf16(a1c, bh[mt][1], acc, 0, 0, 0);
            gm[mt] = fmaxf(gm[mt], fmaxf(fmaxf(acc[0], acc[1]), fmaxf(acc[2], acc[3])));
        }
        if (g + 1 < PCH / GRP) ALOAD(2 * g + 2, a0c, a1c);  // prefetch next even
        #pragma unroll
        for (int mt = 0; mt < 4; ++mt) {            // odd tile MFMAs
            f32x4 acc = {0.f, 0.f, 0.f, 0.f};
            acc = __builtin_amdgcn_mfma_f32_16x16x32_bf16(a0n, bh[mt][0], acc, 0, 0, 0);
            acc = __builtin_amdgcn_mfma_f32_16x16x32_bf16(a1n, bh[mt][1], acc, 0, 0, 0);
            gm[mt] = fmaxf(gm[mt], fmaxf(fmaxf(acc[0], acc[1]), fmaxf(acc[2], acc[3])));
        }

        #pragma unroll
        for (int mt = 0; mt < 4; ++mt) {
            float v = gm[mt];
            v = fmaxf(v, __shfl_xor(v, 16, 64));
            v = fmaxf(v, __shfl_xor(v, 32, 64));
            if (quad == 0)
                gmax[(size_t)(blockIdx.y * (PCH / GRP) + g) * M_TOT + m0 + mt * 16 + col] = v;
        }
    }
    #undef ALOAD
}

// ---------------- Kernel C2: per-row pick + fused loss partial ----------
// One wave per row. Lane l holds groups {l, l+64, l+128, l+192}. Row max via
// shuffle; __ballot flags candidates; wave-parallel exact fp32 rescan (np tie
// rules). Then, bp being wave-uniform, lanes compute the row's (zn-cn[bp])^2
// partial (half-row each, shfl-combined) -> lossp[m]. No LDS, no atomics.
__global__ __launch_bounds__(256)
void k_pick(const float* __restrict__ gmax, const float* __restrict__ zn,
            const float* __restrict__ cn, int* __restrict__ idx_i,
            float* __restrict__ idx_f, float* __restrict__ lossp) {
    int wv = threadIdx.x >> 6, l = threadIdx.x & 63;
    int m = blockIdx.x * 4 + wv;            // one wave per row

    float gv[4];
    #pragma unroll
    for (int b = 0; b < 4; ++b)
        gv[b] = gmax[(size_t)(b * 64 + l) * M_TOT + m];
    float rm = fmaxf(fmaxf(gv[0], gv[1]), fmaxf(gv[2], gv[3]));
    #pragma unroll
    for (int o = 32; o; o >>= 1) rm = fmaxf(rm, __shfl_xor(rm, o, 64));
    float thr = rm - MARG;

    // zn row: lane holds half the row (half = l>>5)
    float zr[32];
    {
        const float4* zp = (const float4*)(zn + (size_t)m * C_DIM + (l >> 5) * 32);
        #pragma unroll
        for (int q = 0; q < 8; ++q) {
            float4 v = zp[q];
            zr[4 * q] = v.x; zr[4 * q + 1] = v.y;
            zr[4 * q + 2] = v.z; zr[4 * q + 3] = v.w;
        }
    }

    float bv = NEG_BIG; int bp = P_DIM;
    #pragma unroll
    for (int b = 0; b < 4; ++b) {           // ascending batches -> ascending groups
        unsigned long long mask = __ballot(gv[b] >= thr);
        while (mask) {
            int j = __ffsll((unsigned long long)mask) - 1;
            mask &= mask - 1;               // ascending j within batch
            int g = b * 64 + j;
            int p = g * GRP + (l & 31);
            const float4* cp = (const float4*)(cn + (size_t)p * C_DIM + (l >> 5) * 32);
            float a0 = 0.f, a1 = 0.f, a2 = 0.f, a3 = 0.f;
            #pragma unroll
            for (int q = 0; q < 8; ++q) {
                float4 w = cp[q];
                a0 = fmaf(w.x, zr[4 * q + 0], a0);
                a1 = fmaf(w.y, zr[4 * q + 1], a1);
                a2 = fmaf(w.z, zr[4 * q + 2], a2);
                a3 = fmaf(w.w, zr[4 * q + 3], a3);
            }
            float s = (a0 + a1) + (a2 + a3);
            s += __shfl_xor(s, 32, 64);     // combine halves: full dot in both lanes
            if (s > bv || (s == bv && p < bp)) { bv = s; bp = p; }
        }
    }
    #pragma unroll
    for (int o = 32; o; o >>= 1) {
        float ov = __shfl_xor(bv, o, 64);
        int   op = __shfl_xor(bp, o, 64);
        if (ov > bv || (ov == bv && op < bp)) { bv = ov; bp = op; }
    }
    if (l == 0) { idx_i[m] = bp; idx_f[m] = (float)bp; }

    // fused loss partial: sum (zn - cn[bp])^2 over the row (bp wave-uniform)
    {
        const float4* cp = (const float4*)(cn + (size_t)bp * C_DIM + (l >> 5) * 32);
        float d2 = 0.f;
        #pragma unroll
        for (int q = 0; q < 8; ++q) {
            float4 w = cp[q];
            float dx = zr[4 * q + 0] - w.x; d2 = fmaf(dx, dx, d2);
            float dy = zr[4 * q + 1] - w.y; d2 = fmaf(dy, dy, d2);
            float dz = zr[4 * q + 2] - w.z; d2 = fmaf(dz, dz, d2);
            float dw = zr[4 * q + 3] - w.w; d2 = fmaf(dw, dw, d2);
        }
        d2 += __shfl_xor(d2, 32, 64);
        if (l == 0) lossp[m] = d2;
    }
}

// ---------------- Kernel D: out = codes @ w_outT ----------------
#define D_ROWS 128
__global__ void k_out(const int* __restrict__ idx, const float* __restrict__ cn,
                      const float* __restrict__ wT, float* __restrict__ out) {
    int wv = threadIdx.x >> 6, lane = threadIdx.x & 63;
    int f  = blockIdx.y * 64 + lane;
    int m0 = blockIdx.x * D_ROWS + wv * 32;

    float wcol[64];
    #pragma unroll
    for (int c = 0; c < 64; ++c) wcol[c] = wT[(size_t)c * F_DIM + f];

    #pragma unroll 4
    for (int r = 0; r < 32; ++r) {
        int m = __builtin_amdgcn_readfirstlane(m0 + r);
        const float4* cp = (const float4*)(cn + (size_t)idx[m] * C_DIM);
        float acc = 0.f;
        #pragma unroll
        for (int j = 0; j < 16; ++j) {
            float4 cv = cp[j];
            acc = fmaf(cv.x, wcol[4 * j + 0], acc);
            acc = fmaf(cv.y, wcol[4 * j + 1], acc);
            acc = fmaf(cv.z, wcol[4 * j + 2], acc);
            acc = fmaf(cv.w, wcol[4 * j + 3], acc);
        }
        out[(size_t)m * F_DIM + f] = acc;
    }
}

// ---------------- Kernel F: finalize loss (deterministic) ----------------
__global__ void k_loss_final(const float* __restrict__ lossp, float* __restrict__ loss_out) {
    __shared__ float sh[256];
    float s = 0.f;
    for (int i = threadIdx.x; i < M_TOT; i += 256) s += lossp[i];
    sh[threadIdx.x] = s;
    __syncthreads();
    for (int o = 128; o; o >>= 1) {
        if (threadIdx.x < o) sh[threadIdx.x] += sh[threadIdx.x + o];
        __syncthreads();
    }
    if (threadIdx.x == 0)
        loss_out[0] = 1.25f * sh[0] / (float)(M_TOT * C_DIM);
}

extern "C" void kernel_launch(void* const* d_in, const int* in_sizes, int n_in,
                              void* d_out, int out_size, void* d_ws, size_t ws_size,
                              hipStream_t stream) {
    const float* z     = (const float*)d_in[0];
    const float* w_in  = (const float*)d_in[1];
    const float* w_out = (const float*)d_in[2];
    const float* cb    = (const float*)d_in[3];

    float* out    = (float*)d_out;
    float* lossO  = out + (size_t)M_TOT * F_DIM;
    float* idxO   = lossO + 1;
    // gmax (16.8 MB) lives in the d_out 'out' region: written by k_simmax, read
    // by k_pick, then fully overwritten by k_out afterwards (stream-ordered).
    float* gmax   = out;

    float* ws    = (float*)d_ws;                          // total ~9.4 MB
    float* cn    = ws;                                    // 524288 f   (2 MB)
    float* zn    = cn + (size_t)P_DIM * C_DIM;            // 1048576 f  (4 MB)
    float* wT    = zn + (size_t)M_TOT * C_DIM;            // 49152 f
    float* lossp = wT + (size_t)C_DIM * F_DIM;            // 16384 f
    int*   idxi  = (int*)(lossp + M_TOT);                 // 16384 i
    ushort_t* zh = (ushort_t*)(idxi + M_TOT);             // 1048576 us (2 MB)
    ushort_t* ch = zh + (size_t)M_TOT * C_DIM;            // 524288 us  (1 MB)

    k_norm_cb<<<P_DIM / 4, 256, 0, stream>>>(cb, cn, ch);
    k_transpose_wout<<<(C_DIM * F_DIM) / 256, 256, 0, stream>>>(w_out, wT);
    k_proj<<<M_TOT / PBM, 256, 0, stream>>>(z, w_in, zn, zh);

    dim3 gC(M_TOT / 256, NCH);
    k_simmax<<<gC, 256, 0, stream>>>(zh, ch, gmax);
    k_pick<<<M_TOT / 4, 256, 0, stream>>>(gmax, zn, cn, idxi, idxO, lossp);

    dim3 gD(M_TOT / D_ROWS, F_DIM / 64);
    k_out<<<gD, 256, 0, stream>>>(idxi, cn, wT, out);

    k_loss_final<<<1, 256, 0, stream>>>(lossp, lossO);
}

// Round 15
// 188.479 us; speedup vs baseline: 1.8922x; 1.8922x over previous
//
#include <hip/hip_runtime.h>
#include <hip/hip_bf16.h>
#include <math.h>

#define M_TOT   16384      // B*N = 4*4096
#define F_DIM   768
#define C_DIM   64
#define P_DIM   8192
#define EPSN    1e-12f
#define NEG_BIG (-3.402823466e38f)
#define NCH     16
#define PCH     (P_DIM / NCH)   // 512
#define GRP     32
#define NGRP    (P_DIM / GRP)   // 256
#define MARG    1e-2f           // >= 2 * 4e-3 hard bf16x1 screen error bound

typedef __attribute__((ext_vector_type(8))) short bf16x8;
typedef __attribute__((ext_vector_type(4))) float f32x4;
typedef unsigned short ushort_t;
typedef const __attribute__((address_space(1))) void* gas1_t;
typedef __attribute__((address_space(3))) void* las3_t;

__device__ inline ushort_t bf16hi(float v) {
    __hip_bfloat16 hb = __float2bfloat16(v);
    return *reinterpret_cast<ushort_t*>(&hb);
}

// ---------------- Kernel A: cn = l2norm(codebook) + bf16 round ----------------
__global__ void k_norm_cb(const float* __restrict__ cb, float* __restrict__ cn,
                          ushort_t* __restrict__ ch) {
    int wv = threadIdx.x >> 6, lane = threadIdx.x & 63;
    int row = blockIdx.x * 4 + wv;
    float v = cb[(size_t)row * C_DIM + lane];
    float s = v * v;
    #pragma unroll
    for (int o = 32; o; o >>= 1) s += __shfl_xor(s, o, 64);
    float inv = 1.0f / fmaxf(sqrtf(s), EPSN);
    float nv = v * inv;
    size_t i = (size_t)row * C_DIM + lane;
    cn[i] = nv;
    ch[i] = bf16hi(nv);
}

// ---------------- Kernel A2: w_outT[c][f] = w_out[f][c] ----------------
__global__ void k_transpose_wout(const float* __restrict__ w_out, float* __restrict__ wT) {
    int i = blockIdx.x * 256 + threadIdx.x;   // 49152 total
    int f = i >> 6, c = i & 63;
    wT[(size_t)c * F_DIM + f] = w_out[i];
}

// ---------------- Kernel B: zn = l2norm(z @ w_in^T), tiled fp32 GEMM ----------
// r13's proven version (54-61 us). 256 threads (4 waves) on a 32m x 64c tile.
// z read DIRECT from global (4-row broadcast per wave inst, L1-resident);
// w staged via global_load_lds double-buffer with pre-swizzled source (reads
// use the same XOR involution). Thread = 2x4 acc block. FMA chain per output
// is k-ascending x,y,z,w -- BITWISE identical zn to previous rounds.
#define PBM 32
#define PKC 64
__global__ __launch_bounds__(256)
void k_proj(const float* __restrict__ z, const float* __restrict__ w_in,
            float* __restrict__ zn, ushort_t* __restrict__ zh) {
    __shared__ float lw[2][C_DIM * PKC];   // 2 x 16 KB  [c][slot*4]

    const int t  = threadIdx.x;
    const int m0 = blockIdx.x * PBM;
    const int r0 = (t >> 4) * 2;        // rows r0..r0+1  (t>>4 in 0..15)
    const int c0 = (t & 15) * 4;        // cols c0..c0+3
    const int wswz = t & 15;            // == ((c0+cj)>>2)&15 for cj<4

    const float* zrow[2];
    #pragma unroll
    for (int ri = 0; ri < 2; ++ri)
        zrow[ri] = z + (size_t)(m0 + r0 + ri) * F_DIM;

    float acc[2][4];
    #pragma unroll
    for (int i = 0; i < 2; ++i)
        #pragma unroll
        for (int j = 0; j < 4; ++j) acc[i][j] = 0.0f;

    // stage w chunk 0 into buffer 0 (1024 float4 over 256 thr = 4 each)
    #pragma unroll
    for (int i = 0; i < 4; ++i) {
        int f4 = i * 256 + t; int c = f4 >> 4, s4 = f4 & 15;
        __builtin_amdgcn_global_load_lds(
            (gas1_t)(w_in + (size_t)c * F_DIM + (s4 ^ ((c >> 2) & 15)) * 4),
            (las3_t)(&lw[0][f4 * 4]), 16, 0, 0);
    }
    __syncthreads();

    int cur = 0;
    for (int k0 = 0; k0 < F_DIM; k0 += PKC) {       // 12 chunks
        if (k0 + PKC < F_DIM) {                     // issue next-chunk DMA first
            int nxt = cur ^ 1;
            #pragma unroll
            for (int i = 0; i < 4; ++i) {
                int f4 = i * 256 + t; int c = f4 >> 4, s4 = f4 & 15;
                __builtin_amdgcn_global_load_lds(
                    (gas1_t)(w_in + (size_t)c * F_DIM + k0 + PKC
                             + (s4 ^ ((c >> 2) & 15)) * 4),
                    (las3_t)(&lw[nxt][f4 * 4]), 16, 0, 0);
            }
        }

        const float* lwb = lw[cur];
        #pragma unroll
        for (int kq = 0; kq < 16; ++kq) {
            float4 zf[2], wf[4];
            int wo = (kq ^ wswz) * 4;
            #pragma unroll
            for (int ri = 0; ri < 2; ++ri)
                zf[ri] = *(const float4*)(zrow[ri] + k0 + kq * 4);
            #pragma unroll
            for (int cj = 0; cj < 4; ++cj)
                wf[cj] = *(const float4*)(lwb + (c0 + cj) * PKC + wo);
            #pragma unroll
            for (int ri = 0; ri < 2; ++ri)
                #pragma unroll
                for (int cj = 0; cj < 4; ++cj) {
                    acc[ri][cj] = fmaf(zf[ri].x, wf[cj].x, acc[ri][cj]);
                    acc[ri][cj] = fmaf(zf[ri].y, wf[cj].y, acc[ri][cj]);
                    acc[ri][cj] = fmaf(zf[ri].z, wf[cj].z, acc[ri][cj]);
                    acc[ri][cj] = fmaf(zf[ri].w, wf[cj].w, acc[ri][cj]);
                }
        }
        __syncthreads();    // vmcnt(0)+barrier: next w chunk landed, cur free
        cur ^= 1;
    }

    // ---- epilogue: row-norm (16-lane group holds one row's 64 c) ----
    #pragma unroll
    for (int ri = 0; ri < 2; ++ri) {
        float s = acc[ri][0] * acc[ri][0] + acc[ri][1] * acc[ri][1]
                + acc[ri][2] * acc[ri][2] + acc[ri][3] * acc[ri][3];
        #pragma unroll
        for (int o = 1; o < 16; o <<= 1) s += __shfl_xor(s, o, 64);
        float inv = 1.0f / fmaxf(sqrtf(s), EPSN);
        float4 v;
        v.x = acc[ri][0] * inv; v.y = acc[ri][1] * inv;
        v.z = acc[ri][2] * inv; v.w = acc[ri][3] * inv;
        size_t base = (size_t)(m0 + r0 + ri) * C_DIM + c0;
        *(float4*)(zn + base) = v;
        ushort4 hv = {bf16hi(v.x), bf16hi(v.y), bf16hi(v.z), bf16hi(v.w)};
        *(ushort4*)(zh + base) = hv;
    }
}

// ---------------- Kernel C: bf16x1 MFMA screen -> per-32-code group maxima ----------
// r11's proven version (best total 195.6): plain per-tile loads, no reg-dbuf,
// NCH=16, 4 waves/EU. Single-precision screen: |err| <= 4e-3 hard; k_pick
// rescans in exact fp32 with MARG = 1e-2 >= 2*err. gmax[NGRP][M_TOT] in d_out.
__global__ __launch_bounds__(256, 4)
void k_simmax(const ushort_t* __restrict__ zh, const ushort_t* __restrict__ ch,
              float* __restrict__ gmax) {
    int wv = threadIdx.x >> 6, l = threadIdx.x & 63;
    int m0 = (blockIdx.x * 4 + wv) * 64;
    int p0 = blockIdx.y * PCH;
    int col = l & 15, quad = l >> 4;
    int kb = quad * 8;

    bf16x8 bh[4][2];
    #pragma unroll
    for (int mt = 0; mt < 4; ++mt) {
        const ushort_t* zr = zh + (size_t)(m0 + mt * 16 + col) * C_DIM + kb;
        #pragma unroll
        for (int ks = 0; ks < 2; ++ks)
            bh[mt][ks] = *(const bf16x8*)(zr + ks * 32);
    }

    for (int g = 0; g < PCH / GRP; ++g) {           // 16 groups of 32 p
        float gm[4];
        #pragma unroll
        for (int mt = 0; mt < 4; ++mt) gm[mt] = NEG_BIG;

        #pragma unroll
        for (int half = 0; half < 2; ++half) {      // 2 16-p tiles per group
            int pt = g * 2 + half;
            size_t prow = (size_t)(p0 + pt * 16 + col) * C_DIM + kb;
            bf16x8 ah0 = *(const bf16x8*)(ch + prow);
            bf16x8 ah1 = *(const bf16x8*)(ch + prow + 32);
            #pragma unroll
            for (int mt = 0; mt < 4; ++mt) {
                f32x4 acc = {0.f, 0.f, 0.f, 0.f};
                acc = __builtin_amdgcn_mfma_f32_16x16x32_bf16(ah0, bh[mt][0], acc, 0, 0, 0);
                acc = __builtin_amdgcn_mfma_f32_16x16x32_bf16(ah1, bh[mt][1], acc, 0, 0, 0);
                float tm = fmaxf(fmaxf(acc[0], acc[1]), fmaxf(acc[2], acc[3]));
                gm[mt] = fmaxf(gm[mt], tm);
            }
        }
        #pragma unroll
        for (int mt = 0; mt < 4; ++mt) {
            float v = gm[mt];
            v = fmaxf(v, __shfl_xor(v, 16, 64));
            v = fmaxf(v, __shfl_xor(v, 32, 64));
            if (quad == 0)
                gmax[(size_t)(blockIdx.y * (PCH / GRP) + g) * M_TOT + m0 + mt * 16 + col] = v;
        }
    }
}

// ---------------- Kernel C2: per-row pick + fused loss partial ----------
// One wave per row. Lane l holds groups {l, l+64, l+128, l+192}. Row max via
// shuffle; __ballot flags candidates; wave-parallel exact fp32 rescan (np tie
// rules). Then, bp being wave-uniform, lanes compute the row's (zn-cn[bp])^2
// partial (half-row each, shfl-combined) -> lossp[m]. No LDS, no atomics.
__global__ __launch_bounds__(256)
void k_pick(const float* __restrict__ gmax, const float* __restrict__ zn,
            const float* __restrict__ cn, int* __restrict__ idx_i,
            float* __restrict__ idx_f, float* __restrict__ lossp) {
    int wv = threadIdx.x >> 6, l = threadIdx.x & 63;
    int m = blockIdx.x * 4 + wv;            // one wave per row

    float gv[4];
    #pragma unroll
    for (int b = 0; b < 4; ++b)
        gv[b] = gmax[(size_t)(b * 64 + l) * M_TOT + m];
    float rm = fmaxf(fmaxf(gv[0], gv[1]), fmaxf(gv[2], gv[3]));
    #pragma unroll
    for (int o = 32; o; o >>= 1) rm = fmaxf(rm, __shfl_xor(rm, o, 64));
    float thr = rm - MARG;

    // zn row: lane holds half the row (half = l>>5)
    float zr[32];
    {
        const float4* zp = (const float4*)(zn + (size_t)m * C_DIM + (l >> 5) * 32);
        #pragma unroll
        for (int q = 0; q < 8; ++q) {
            float4 v = zp[q];
            zr[4 * q] = v.x; zr[4 * q + 1] = v.y;
            zr[4 * q + 2] = v.z; zr[4 * q + 3] = v.w;
        }
    }

    float bv = NEG_BIG; int bp = P_DIM;
    #pragma unroll
    for (int b = 0; b < 4; ++b) {           // ascending batches -> ascending groups
        unsigned long long mask = __ballot(gv[b] >= thr);
        while (mask) {
            int j = __ffsll((unsigned long long)mask) - 1;
            mask &= mask - 1;               // ascending j within batch
            int g = b * 64 + j;
            int p = g * GRP + (l & 31);
            const float4* cp = (const float4*)(cn + (size_t)p * C_DIM + (l >> 5) * 32);
            float a0 = 0.f, a1 = 0.f, a2 = 0.f, a3 = 0.f;
            #pragma unroll
            for (int q = 0; q < 8; ++q) {
                float4 w = cp[q];
                a0 = fmaf(w.x, zr[4 * q + 0], a0);
                a1 = fmaf(w.y, zr[4 * q + 1], a1);
                a2 = fmaf(w.z, zr[4 * q + 2], a2);
                a3 = fmaf(w.w, zr[4 * q + 3], a3);
            }
            float s = (a0 + a1) + (a2 + a3);
            s += __shfl_xor(s, 32, 64);     // combine halves: full dot in both lanes
            if (s > bv || (s == bv && p < bp)) { bv = s; bp = p; }
        }
    }
    #pragma unroll
    for (int o = 32; o; o >>= 1) {
        float ov = __shfl_xor(bv, o, 64);
        int   op = __shfl_xor(bp, o, 64);
        if (ov > bv || (ov == bv && op < bp)) { bv = ov; bp = op; }
    }
    if (l == 0) { idx_i[m] = bp; idx_f[m] = (float)bp; }

    // fused loss partial: sum (zn - cn[bp])^2 over the row (bp wave-uniform)
    {
        const float4* cp = (const float4*)(cn + (size_t)bp * C_DIM + (l >> 5) * 32);
        float d2 = 0.f;
        #pragma unroll
        for (int q = 0; q < 8; ++q) {
            float4 w = cp[q];
            float dx = zr[4 * q + 0] - w.x; d2 = fmaf(dx, dx, d2);
            float dy = zr[4 * q + 1] - w.y; d2 = fmaf(dy, dy, d2);
            float dz = zr[4 * q + 2] - w.z; d2 = fmaf(dz, dz, d2);
            float dw = zr[4 * q + 3] - w.w; d2 = fmaf(dw, dw, d2);
        }
        d2 += __shfl_xor(d2, 32, 64);
        if (l == 0) lossp[m] = d2;
    }
}

// ---------------- Kernel D: out = codes @ w_outT, 4 independent FMA chains ----
// Per row the dot is split into 4 partial chains (a0..a3) combined at the end:
// 4x the ILP of the single-chain version (dependent-latency bound). Summation
// reorder shifts out by ~1e-6, far below the output threshold; out feeds nothing.
#define D_ROWS 128
__global__ void k_out(const int* __restrict__ idx, const float* __restrict__ cn,
                      const float* __restrict__ wT, float* __restrict__ out) {
    int wv = threadIdx.x >> 6, lane = threadIdx.x & 63;
    int f  = blockIdx.y * 64 + lane;
    int m0 = blockIdx.x * D_ROWS + wv * 32;

    float wcol[64];
    #pragma unroll
    for (int c = 0; c < 64; ++c) wcol[c] = wT[(size_t)c * F_DIM + f];

    #pragma unroll 4
    for (int r = 0; r < 32; ++r) {
        int m = __builtin_amdgcn_readfirstlane(m0 + r);
        const float4* cp = (const float4*)(cn + (size_t)idx[m] * C_DIM);
        float a0 = 0.f, a1 = 0.f, a2 = 0.f, a3 = 0.f;
        #pragma unroll
        for (int j = 0; j < 16; ++j) {
            float4 cv = cp[j];
            a0 = fmaf(cv.x, wcol[4 * j + 0], a0);
            a1 = fmaf(cv.y, wcol[4 * j + 1], a1);
            a2 = fmaf(cv.z, wcol[4 * j + 2], a2);
            a3 = fmaf(cv.w, wcol[4 * j + 3], a3);
        }
        out[(size_t)m * F_DIM + f] = (a0 + a1) + (a2 + a3);
    }
}

// ---------------- Kernel F: finalize loss (deterministic) ----------------
__global__ void k_loss_final(const float* __restrict__ lossp, float* __restrict__ loss_out) {
    __shared__ float sh[256];
    float s = 0.f;
    for (int i = threadIdx.x; i < M_TOT; i += 256) s += lossp[i];
    sh[threadIdx.x] = s;
    __syncthreads();
    for (int o = 128; o; o >>= 1) {
        if (threadIdx.x < o) sh[threadIdx.x] += sh[threadIdx.x + o];
        __syncthreads();
    }
    if (threadIdx.x == 0)
        loss_out[0] = 1.25f * sh[0] / (float)(M_TOT * C_DIM);
}

extern "C" void kernel_launch(void* const* d_in, const int* in_sizes, int n_in,
                              void* d_out, int out_size, void* d_ws, size_t ws_size,
                              hipStream_t stream) {
    const float* z     = (const float*)d_in[0];
    const float* w_in  = (const float*)d_in[1];
    const float* w_out = (const float*)d_in[2];
    const float* cb    = (const float*)d_in[3];

    float* out    = (float*)d_out;
    float* lossO  = out + (size_t)M_TOT * F_DIM;
    float* idxO   = lossO + 1;
    // gmax (16.8 MB) lives in the d_out 'out' region: written by k_simmax, read
    // by k_pick, then fully overwritten by k_out afterwards (stream-ordered).
    float* gmax   = out;

    float* ws    = (float*)d_ws;                          // total ~9.4 MB
    float* cn    = ws;                                    // 524288 f   (2 MB)
    float* zn    = cn + (size_t)P_DIM * C_DIM;            // 1048576 f  (4 MB)
    float* wT    = zn + (size_t)M_TOT * C_DIM;            // 49152 f
    float* lossp = wT + (size_t)C_DIM * F_DIM;            // 16384 f
    int*   idxi  = (int*)(lossp + M_TOT);                 // 16384 i
    ushort_t* zh = (ushort_t*)(idxi + M_TOT);             // 1048576 us (2 MB)
    ushort_t* ch = zh + (size_t)M_TOT * C_DIM;            // 524288 us  (1 MB)

    k_norm_cb<<<P_DIM / 4, 256, 0, stream>>>(cb, cn, ch);
    k_transpose_wout<<<(C_DIM * F_DIM) / 256, 256, 0, stream>>>(w_out, wT);
    k_proj<<<M_TOT / PBM, 256, 0, stream>>>(z, w_in, zn, zh);

    dim3 gC(M_TOT / 256, NCH);
    k_simmax<<<gC, 256, 0, stream>>>(zh, ch, gmax);
    k_pick<<<M_TOT / 4, 256, 0, stream>>>(gmax, zn, cn, idxi, idxO, lossp);

    dim3 gD(M_TOT / D_ROWS, F_DIM / 64);
    k_out<<<gD, 256, 0, stream>>>(idxi, cn, wT, out);

    k_loss_final<<<1, 256, 0, stream>>>(lossp, lossO);
}